// Round 2
// baseline (479.052 us; speedup 1.0000x reference)
//
#include <hip/hip_runtime.h>
#include <hip/hip_bf16.h>

#define N_NODES 100000
#define F_IN    256
#define H_DIM   128
#define C_CLS   16
#define NB_SCAN ((N_NODES + 255) / 256)   // 391

typedef __attribute__((ext_vector_type(8))) short  short8;
typedef __attribute__((ext_vector_type(4))) float  float4v;
typedef __attribute__((ext_vector_type(4))) unsigned short ushort4v;

__device__ __forceinline__ float b2f(ushort u) {
    union { unsigned int i; float f; } v;
    v.i = ((unsigned int)u) << 16;
    return v.f;
}

__device__ __forceinline__ ushort f2b(float f) {
    unsigned int x = __float_as_uint(f);
    unsigned int r = (x + 0x7FFFu + ((x >> 16) & 1u)) >> 16;   // RNE
    return (ushort)r;
}

__device__ __forceinline__ float ldsel(const void* p, int i, int f32f) {
    return f32f ? ((const float*)p)[i] : b2f(((const ushort*)p)[i]);
}

// ------------------------------------------------------------------ sniff ---
__global__ __launch_bounds__(64) void sniff(const ushort* __restrict__ x,
                                            const int* __restrict__ ei,
                                            int* __restrict__ flags) {
    int lane = threadIdx.x;
    int cnt_bf = 0;
#pragma unroll
    for (int j = 0; j < 4; ++j) {
        ushort u = x[lane * 4 + j];
        int e = (u >> 7) & 0xFF;
        if ((e >= 100 && e <= 140) || (u & 0x7FFF) == 0) cnt_bf++;
    }
    int zodd = (ei[2 * lane + 1] == 0) ? 1 : 0;
#pragma unroll
    for (int off = 32; off >= 1; off >>= 1) {
        cnt_bf += __shfl_xor(cnt_bf, off, 64);
        zodd   += __shfl_xor(zodd,   off, 64);
    }
    if (lane == 0) {
        flags[0] = (cnt_bf < 230) ? 1 : 0;   // f32 inputs
        flags[1] = (zodd  >= 32) ? 1 : 0;    // int64 indices
    }
}

// ------------------------------------------------ f32 -> bf16 for W only ----
__global__ __launch_bounds__(256) void convert_w(const int* __restrict__ flags,
                                                 const float* __restrict__ Wf,
                                                 ushort* __restrict__ wb) {
    if (flags[0] == 0) return;
    int i = (blockIdx.x * 256 + threadIdx.x) * 4;   // grid covers F_IN*H exactly
    float4 v = *(const float4*)(Wf + i);
    ushort4v o;
    o[0] = f2b(v.x); o[1] = f2b(v.y); o[2] = f2b(v.z); o[3] = f2b(v.w);
    *(ushort4v*)(wb + i) = o;
}

// ------------- precompute bayes weights (bf16 hi+lo), bias, gcn bias --------
__global__ __launch_bounds__(512) void make_w(const int* __restrict__ flags,
                                              const void* __restrict__ w_mu,
                                              const void* __restrict__ w_ls,
                                              const void* __restrict__ eps_w,
                                              const void* __restrict__ b_mu,
                                              const void* __restrict__ b_ls,
                                              const void* __restrict__ eps_b,
                                              const void* __restrict__ gcn_b,
                                              ushort* __restrict__ whi,
                                              ushort* __restrict__ wlo,
                                              float* __restrict__ bias16,
                                              float* __restrict__ gcnb_f) {
    const int f32f = flags[0];
    const int t = threadIdx.x;
#pragma unroll
    for (int i = t; i < C_CLS * H_DIM; i += 512) {
        float v = ldsel(w_mu, i, f32f) + __expf(ldsel(w_ls, i, f32f)) * ldsel(eps_w, i, f32f);
        ushort h = f2b(v);
        whi[i] = h;
        wlo[i] = f2b(v - b2f(h));     // residual: recovers ~16-bit mantissa
    }
    if (t < C_CLS)
        bias16[t] = ldsel(b_mu, t, f32f) + __expf(ldsel(b_ls, t, f32f)) * ldsel(eps_b, t, f32f);
    if (t < H_DIM)
        gcnb_f[t] = ldsel(gcn_b, t, f32f);
}

// ---------------------- prep: degree count only (reads dst half of ei) ------
__global__ __launch_bounds__(256) void prep(const int* __restrict__ flags,
                                            const int* __restrict__ ei,
                                            int* __restrict__ cnt, int E) {
    int e = blockIdx.x * 256 + threadIdx.x;
    if (e >= E) return;
    int d = flags[1] ? ei[2L * E + 2L * e] : ei[(long)E + e];
    atomicAdd(&cnt[d], 1);
}

// ------------------------------------------------------------ 3-step scan ---
__global__ __launch_bounds__(256) void scan1(const int* __restrict__ cnt,
                                             int* __restrict__ offs,
                                             int* __restrict__ bsum) {
    __shared__ int sd[256];
    int t = threadIdx.x;
    int i = blockIdx.x * 256 + t;
    int v = (i < N_NODES) ? cnt[i] : 0;
    sd[t] = v;
    __syncthreads();
#pragma unroll
    for (int d = 1; d < 256; d <<= 1) {
        int add = (t >= d) ? sd[t - d] : 0;
        __syncthreads();
        sd[t] += add;
        __syncthreads();
    }
    if (i < N_NODES) offs[i] = sd[t] - v;          // exclusive within block
    if (t == 255) bsum[blockIdx.x] = sd[255];
}

__global__ __launch_bounds__(512) void scan2(const int* __restrict__ bsum,
                                             int* __restrict__ boff) {
    __shared__ int sd[512];
    int t = threadIdx.x;
    int v = (t < NB_SCAN) ? bsum[t] : 0;
    sd[t] = v;
    __syncthreads();
#pragma unroll
    for (int d = 1; d < 512; d <<= 1) {
        int add = (t >= d) ? sd[t - d] : 0;
        __syncthreads();
        sd[t] += add;
        __syncthreads();
    }
    if (t < NB_SCAN) boff[t] = sd[t] - v;          // exclusive
}

// offs -> global offsets; also cursor copy and dis = rsqrt(deg) fused
__global__ __launch_bounds__(256) void scan3(int* __restrict__ offs,
                                             const int* __restrict__ boff,
                                             const int* __restrict__ cnt,
                                             int* __restrict__ cursor,
                                             float* __restrict__ dis, int E) {
    int i = blockIdx.x * 256 + threadIdx.x;
    if (i == 0) offs[N_NODES] = E;
    if (i >= N_NODES) return;
    int off = offs[i] + boff[i >> 8];
    offs[i] = off;
    cursor[i] = off;
    dis[i] = rsqrtf((float)(cnt[i] + 1));          // +1 self-loop
}

// ------------------------------------------------------ permutation build ---
// Reads ei directly (no src32/dst32 intermediates). Payload is 4B: just src.
// The dis[src] weight is gone -- it's folded into hb (h' = h * dis) in the
// gemm epilogue, so agg = dis[d] * (sum h'[s] + h'[d]).
__global__ __launch_bounds__(256) void build_perm(const int* __restrict__ flags,
                                                  const int* __restrict__ ei,
                                                  int* __restrict__ cursor,
                                                  int* __restrict__ perm, int E) {
    int e = blockIdx.x * 256 + threadIdx.x;
    if (e >= E) return;
    int i64 = flags[1];
    int s = i64 ? ei[2L * e]          : ei[e];
    int d = i64 ? ei[2L * E + 2L * e] : ei[(long)E + e];
    int slot = atomicAdd(&cursor[d], 1);
    perm[slot] = s;
}

// ------------------------------------------------- h' = (x @ W) * dis -------
__global__ __launch_bounds__(256) void gemm_xw(const int* __restrict__ flags,
                                               const void* __restrict__ x_any,
                                               const ushort* __restrict__ W_raw,
                                               const ushort* __restrict__ wb,
                                               const float* __restrict__ dis,
                                               ushort* __restrict__ hout) {
    __shared__ __align__(16) ushort wt[128][128 + 8];   // 34816 B
    const int f32f = flags[0];
    const ushort* W = f32f ? wb : W_raw;

    const int tid  = threadIdx.x;
    const int lane = tid & 63;
    const int wave = tid >> 6;
    const int quad = lane >> 4;
    const int lm   = lane & 15;

    const int rbase = blockIdx.x * 64 + wave * 16;
    int arow = rbase + lm;
    if (arow >= N_NODES) arow = N_NODES - 1;      // clamp; store is guarded
    const float*  xrf = (const float*) x_any + (size_t)arow * F_IN;
    const ushort* xrb = (const ushort*)x_any + (size_t)arow * F_IN;

    float4v acc[8];
#pragma unroll
    for (int c = 0; c < 8; ++c) acc[c] = (float4v){0.f, 0.f, 0.f, 0.f};

    for (int hh = 0; hh < 2; ++hh) {
        if (hh) __syncthreads();
#pragma unroll
        for (int it = 0; it < 8; ++it) {
            int flat = (it * 256 + tid) * 8;       // 0..16384
            int kl = flat >> 7;
            int c0 = flat & 127;
            short8 v = *(const short8*)(W + hh * 16384 + flat);
#pragma unroll
            for (int j = 0; j < 8; ++j) wt[c0 + j][kl] = (ushort)v[j];
        }
        __syncthreads();
#pragma unroll
        for (int s = 0; s < 4; ++s) {
            int klocal = s * 32 + quad * 8;
            short8 afrag;
            if (f32f) {
                const float* p = xrf + hh * 128 + klocal;
                float4 u0 = *(const float4*)p;
                float4 u1 = *(const float4*)(p + 4);
                afrag[0] = (short)f2b(u0.x); afrag[1] = (short)f2b(u0.y);
                afrag[2] = (short)f2b(u0.z); afrag[3] = (short)f2b(u0.w);
                afrag[4] = (short)f2b(u1.x); afrag[5] = (short)f2b(u1.y);
                afrag[6] = (short)f2b(u1.z); afrag[7] = (short)f2b(u1.w);
            } else {
                afrag = *(const short8*)(xrb + hh * 128 + klocal);
            }
#pragma unroll
            for (int c = 0; c < 8; ++c) {
                short8 bfrag = *(const short8*)(&wt[c * 16 + lm][klocal]);
                acc[c] = __builtin_amdgcn_mfma_f32_16x16x32_bf16(afrag, bfrag, acc[c], 0, 0, 0);
            }
        }
    }
    // D[row=quad*4+r][col=lane&15]; scale rows by dis[node] before rounding
    float dv[4];
#pragma unroll
    for (int r = 0; r < 4; ++r) {
        int node = rbase + quad * 4 + r;
        dv[r] = (node < N_NODES) ? dis[node] : 0.f;
    }
#pragma unroll
    for (int c = 0; c < 8; ++c) {
        int col = c * 16 + lm;
#pragma unroll
        for (int r = 0; r < 4; ++r) {
            int node = rbase + quad * 4 + r;
            if (node < N_NODES) hout[(size_t)node * H_DIM + col] = f2b(acc[c][r] * dv[r]);
        }
    }
}

// --------------------- gather-reduce + bias + relu -> a (bf16) --------------
// One wave per node; lane owns cols {2l, 2l+1}. off0/deg are wave-uniform and
// forced to SGPR via readfirstlane, so the src list is read with SCALAR 4B
// loads. No per-edge weight: hb rows are pre-scaled by dis[src]; the wave
// just sums rows, adds the self row, scales once by dis[node], bias, relu.
__global__ __launch_bounds__(256) void gather_relu(const int* __restrict__ offs,
                                                   const int* __restrict__ perm,
                                                   const float* __restrict__ dis,
                                                   const ushort* __restrict__ hb,
                                                   const float* __restrict__ gcnb_f,
                                                   ushort* __restrict__ aout) {
    const int lane = threadIdx.x & 63;
    const int node = blockIdx.x * 4 + (threadIdx.x >> 6);
    if (node >= N_NODES) return;

    const int off0 = __builtin_amdgcn_readfirstlane(offs[node]);
    const int deg  = __builtin_amdgcn_readfirstlane(offs[node + 1]) - off0;
    const int* pp = perm + off0;

    float ax = 0.f, ay = 0.f;
    const int full = deg & ~15;
    for (int base = 0; base < full; base += 16) {
#pragma unroll
        for (int k = 0; k < 16; ++k) {
            int sk = pp[base + k];                  // scalar 4B load (uniform)
            uint u = *((const uint*)(hb + (size_t)sk * H_DIM) + lane);
            ax += __uint_as_float(u << 16);
            ay += __uint_as_float(u & 0xFFFF0000u);
        }
    }
    {
        const int nb = deg - full;                  // 0..15, uniform
#pragma unroll
        for (int k = 0; k < 16; ++k) {
            int   sk = 0;
            float wk = 0.f;
            if (k < nb) { sk = pp[full + k]; wk = 1.f; }
            uint u = *((const uint*)(hb + (size_t)sk * H_DIM) + lane);
            ax = fmaf(wk, __uint_as_float(u << 16),         ax);
            ay = fmaf(wk, __uint_as_float(u & 0xFFFF0000u), ay);
        }
    }

    const float dd = dis[node];
    uint us = *((const uint*)(hb + (size_t)node * H_DIM) + lane);   // h'[node]
    float2 gb = *(const float2*)(gcnb_f + 2 * lane);
    ax = (ax + __uint_as_float(us << 16))         * dd + gb.x;
    ay = (ay + __uint_as_float(us & 0xFFFF0000u)) * dd + gb.y;
    ax = fmaxf(ax, 0.f);
    ay = fmaxf(ay, 0.f);
    uint pack = (uint)f2b(ax) | ((uint)f2b(ay) << 16);
    *((uint*)(aout + (size_t)node * H_DIM) + lane) = pack;
}

// -------------------- logits = a @ w^T + b, then log_softmax ----------------
__global__ __launch_bounds__(256) void final_linear(const int* __restrict__ flags,
                                                    const ushort* __restrict__ a,
                                                    const ushort* __restrict__ whi,
                                                    const ushort* __restrict__ wlo,
                                                    const float* __restrict__ bias16,
                                                    void* __restrict__ out) {
    const int f32f = flags[0];
    const int lane = threadIdx.x & 63;
    const int wave = threadIdx.x >> 6;
    const int n0 = (blockIdx.x * 4 + wave) * 16;
    if (n0 >= N_NODES) return;                 // 16 | N_NODES, no partial wave
    const int lm = lane & 15, quad = lane >> 4;

    const ushort* arow = a   + (size_t)(n0 + lm) * H_DIM + quad * 8;
    const ushort* bh   = whi + lm * H_DIM + quad * 8;
    const ushort* bl   = wlo + lm * H_DIM + quad * 8;

    float4v acc = (float4v){0.f, 0.f, 0.f, 0.f};
#pragma unroll
    for (int s = 0; s < 4; ++s) {
        short8 af = *(const short8*)(arow + s * 32);
        short8 b0 = *(const short8*)(bh   + s * 32);
        short8 b1 = *(const short8*)(bl   + s * 32);
        acc = __builtin_amdgcn_mfma_f32_16x16x32_bf16(af, b0, acc, 0, 0, 0);
        acc = __builtin_amdgcn_mfma_f32_16x16x32_bf16(af, b1, acc, 0, 0, 0);
    }

    const float bias = bias16[lm];
    float p[4], m[4], ss[4];
#pragma unroll
    for (int r = 0; r < 4; ++r) { p[r] = acc[r] + bias; m[r] = p[r]; }
#pragma unroll
    for (int off = 1; off < 16; off <<= 1)
#pragma unroll
        for (int r = 0; r < 4; ++r) m[r] = fmaxf(m[r], __shfl_xor(m[r], off, 64));
#pragma unroll
    for (int r = 0; r < 4; ++r) ss[r] = __expf(p[r] - m[r]);
#pragma unroll
    for (int off = 1; off < 16; off <<= 1)
#pragma unroll
        for (int r = 0; r < 4; ++r) ss[r] += __shfl_xor(ss[r], off, 64);

    if (f32f) {
        float* op = (float*)out;
#pragma unroll
        for (int r = 0; r < 4; ++r)
            op[(size_t)(n0 + quad * 4 + r) * C_CLS + lm] = p[r] - m[r] - __logf(ss[r]);
    } else {
        ushort* op = (ushort*)out;
#pragma unroll
        for (int r = 0; r < 4; ++r)
            op[(size_t)(n0 + quad * 4 + r) * C_CLS + lm] = f2b(p[r] - m[r] - __logf(ss[r]));
    }
}

// ---------------------------------------------------------------------------
extern "C" void kernel_launch(void* const* d_in, const int* in_sizes, int n_in,
                              void* d_out, int out_size, void* d_ws, size_t ws_size,
                              hipStream_t stream) {
    const int E = in_sizes[1] / 2;

    char* wp = (char*)d_ws;
    auto alloc = [&](size_t bytes) -> char* {
        char* p = wp; wp += (bytes + 511) & ~(size_t)511; return p;
    };
    int*    flags  = (int*)   alloc(64);
    ushort* hb     = (ushort*)alloc((size_t)N_NODES * H_DIM * 2);   // bf16 h*dis
    ushort* aout   = (ushort*)alloc((size_t)N_NODES * H_DIM * 2);   // bf16 relu(agg)
    int*    cnt    = (int*)   alloc((size_t)N_NODES * 4);
    int*    offs   = (int*)   alloc((size_t)(N_NODES + 1) * 4);
    int*    cursor = (int*)   alloc((size_t)N_NODES * 4);
    int*    bsum   = (int*)   alloc((size_t)NB_SCAN * 4);
    int*    boff   = (int*)   alloc((size_t)NB_SCAN * 4);
    float*  dis    = (float*) alloc((size_t)N_NODES * 4);
    int*    perm   = (int*)   alloc((size_t)E * 4);                 // src only
    ushort* wb     = (ushort*)alloc((size_t)F_IN * H_DIM * 2);
    ushort* whi    = (ushort*)alloc((size_t)C_CLS * H_DIM * 2);
    ushort* wlo    = (ushort*)alloc((size_t)C_CLS * H_DIM * 2);
    float*  bias16 = (float*) alloc((size_t)C_CLS * 4);
    float*  gcnb_f = (float*) alloc((size_t)H_DIM * 4);

    sniff<<<1, 64, 0, stream>>>((const ushort*)d_in[0], (const int*)d_in[1], flags);
    convert_w<<<(F_IN * H_DIM / 4 + 255) / 256, 256, 0, stream>>>(
        flags, (const float*)d_in[2], wb);
    make_w<<<1, 512, 0, stream>>>(flags, d_in[4], d_in[5], d_in[8],
                                  d_in[6], d_in[7], d_in[9], d_in[3],
                                  whi, wlo, bias16, gcnb_f);
    (void)hipMemsetAsync(cnt, 0, (size_t)N_NODES * 4, stream);
    prep<<<(E + 255) / 256, 256, 0, stream>>>(flags, (const int*)d_in[1], cnt, E);
    scan1<<<NB_SCAN, 256, 0, stream>>>(cnt, offs, bsum);
    scan2<<<1, 512, 0, stream>>>(bsum, boff);
    scan3<<<NB_SCAN, 256, 0, stream>>>(offs, boff, cnt, cursor, dis, E);
    build_perm<<<(E + 255) / 256, 256, 0, stream>>>(flags, (const int*)d_in[1], cursor, perm, E);
    gemm_xw<<<(N_NODES + 63) / 64, 256, 0, stream>>>(flags, d_in[0],
                 (const ushort*)d_in[2], wb, dis, hb);
    gather_relu<<<(N_NODES + 3) / 4, 256, 0, stream>>>(offs, perm, dis, hb, gcnb_f, aout);
    final_linear<<<(N_NODES / C_CLS + 3) / 4, 256, 0, stream>>>(flags, aout, whi, wlo, bias16, (void*)d_out);
}

// Round 3
// 435.432 us; speedup vs baseline: 1.1002x; 1.1002x over previous
//
#include <hip/hip_runtime.h>
#include <hip/hip_bf16.h>

#define N_NODES 100000
#define F_IN    256
#define H_DIM   128
#define C_CLS   16
#define NB_SCAN ((N_NODES + 255) / 256)   // 391
#define NSHARD  8
#define SHARD_W ((N_NODES + NSHARD - 1) / NSHARD)   // 12500

typedef __attribute__((ext_vector_type(8))) short  short8;
typedef __attribute__((ext_vector_type(4))) float  float4v;
typedef __attribute__((ext_vector_type(4))) unsigned short ushort4v;

__device__ __forceinline__ float b2f(ushort u) {
    union { unsigned int i; float f; } v;
    v.i = ((unsigned int)u) << 16;
    return v.f;
}

__device__ __forceinline__ ushort f2b(float f) {
    unsigned int x = __float_as_uint(f);
    unsigned int r = (x + 0x7FFFu + ((x >> 16) & 1u)) >> 16;   // RNE
    return (ushort)r;
}

__device__ __forceinline__ float ldsel(const void* p, int i, int f32f) {
    return f32f ? ((const float*)p)[i] : b2f(((const ushort*)p)[i]);
}

// ------------------------------------------------------------------ sniff ---
__global__ __launch_bounds__(64) void sniff(const ushort* __restrict__ x,
                                            const int* __restrict__ ei,
                                            int* __restrict__ flags) {
    int lane = threadIdx.x;
    int cnt_bf = 0;
#pragma unroll
    for (int j = 0; j < 4; ++j) {
        ushort u = x[lane * 4 + j];
        int e = (u >> 7) & 0xFF;
        if ((e >= 100 && e <= 140) || (u & 0x7FFF) == 0) cnt_bf++;
    }
    int zodd = (ei[2 * lane + 1] == 0) ? 1 : 0;
#pragma unroll
    for (int off = 32; off >= 1; off >>= 1) {
        cnt_bf += __shfl_xor(cnt_bf, off, 64);
        zodd   += __shfl_xor(zodd,   off, 64);
    }
    if (lane == 0) {
        flags[0] = (cnt_bf < 230) ? 1 : 0;   // f32 inputs
        flags[1] = (zodd  >= 32) ? 1 : 0;    // int64 indices
    }
}

// ------------------------------------------------ f32 -> bf16 for W only ----
__global__ __launch_bounds__(256) void convert_w(const int* __restrict__ flags,
                                                 const float* __restrict__ Wf,
                                                 ushort* __restrict__ wb) {
    if (flags[0] == 0) return;
    int i = (blockIdx.x * 256 + threadIdx.x) * 4;   // grid covers F_IN*H exactly
    float4 v = *(const float4*)(Wf + i);
    ushort4v o;
    o[0] = f2b(v.x); o[1] = f2b(v.y); o[2] = f2b(v.z); o[3] = f2b(v.w);
    *(ushort4v*)(wb + i) = o;
}

// ------------- precompute bayes weights (bf16 hi+lo), bias, gcn bias --------
__global__ __launch_bounds__(512) void make_w(const int* __restrict__ flags,
                                              const void* __restrict__ w_mu,
                                              const void* __restrict__ w_ls,
                                              const void* __restrict__ eps_w,
                                              const void* __restrict__ b_mu,
                                              const void* __restrict__ b_ls,
                                              const void* __restrict__ eps_b,
                                              const void* __restrict__ gcn_b,
                                              ushort* __restrict__ whi,
                                              ushort* __restrict__ wlo,
                                              float* __restrict__ bias16,
                                              float* __restrict__ gcnb_f) {
    const int f32f = flags[0];
    const int t = threadIdx.x;
#pragma unroll
    for (int i = t; i < C_CLS * H_DIM; i += 512) {
        float v = ldsel(w_mu, i, f32f) + __expf(ldsel(w_ls, i, f32f)) * ldsel(eps_w, i, f32f);
        ushort h = f2b(v);
        whi[i] = h;
        wlo[i] = f2b(v - b2f(h));     // residual: recovers ~16-bit mantissa
    }
    if (t < C_CLS)
        bias16[t] = ldsel(b_mu, t, f32f) + __expf(ldsel(b_ls, t, f32f)) * ldsel(eps_b, t, f32f);
    if (t < H_DIM)
        gcnb_f[t] = ldsel(gcn_b, t, f32f);
}

// ---------------------- prep: degree count only (reads dst half of ei) ------
__global__ __launch_bounds__(256) void prep(const int* __restrict__ flags,
                                            const int* __restrict__ ei,
                                            int* __restrict__ cnt, int E) {
    int e = blockIdx.x * 256 + threadIdx.x;
    if (e >= E) return;
    int d = flags[1] ? ei[2L * E + 2L * e] : ei[(long)E + e];
    atomicAdd(&cnt[d], 1);
}

// ------------------------------------------------------------ 3-step scan ---
__global__ __launch_bounds__(256) void scan1(const int* __restrict__ cnt,
                                             int* __restrict__ offs,
                                             int* __restrict__ bsum) {
    __shared__ int sd[256];
    int t = threadIdx.x;
    int i = blockIdx.x * 256 + t;
    int v = (i < N_NODES) ? cnt[i] : 0;
    sd[t] = v;
    __syncthreads();
#pragma unroll
    for (int d = 1; d < 256; d <<= 1) {
        int add = (t >= d) ? sd[t - d] : 0;
        __syncthreads();
        sd[t] += add;
        __syncthreads();
    }
    if (i < N_NODES) offs[i] = sd[t] - v;          // exclusive within block
    if (t == 255) bsum[blockIdx.x] = sd[255];
}

__global__ __launch_bounds__(512) void scan2(const int* __restrict__ bsum,
                                             int* __restrict__ boff) {
    __shared__ int sd[512];
    int t = threadIdx.x;
    int v = (t < NB_SCAN) ? bsum[t] : 0;
    sd[t] = v;
    __syncthreads();
#pragma unroll
    for (int d = 1; d < 512; d <<= 1) {
        int add = (t >= d) ? sd[t - d] : 0;
        __syncthreads();
        sd[t] += add;
        __syncthreads();
    }
    if (t < NB_SCAN) boff[t] = sd[t] - v;          // exclusive
}

// offs -> global offsets; also cursor copy and dis = rsqrt(deg) fused
__global__ __launch_bounds__(256) void scan3(int* __restrict__ offs,
                                             const int* __restrict__ boff,
                                             const int* __restrict__ cnt,
                                             int* __restrict__ cursor,
                                             float* __restrict__ dis, int E) {
    int i = blockIdx.x * 256 + threadIdx.x;
    if (i == 0) offs[N_NODES] = E;
    if (i >= N_NODES) return;
    int off = offs[i] + boff[i >> 8];
    offs[i] = off;
    cursor[i] = off;
    dis[i] = rsqrtf((float)(cnt[i] + 1));          // +1 self-loop
}

// ---------------------------------- XCD-sharded permutation build -----------
// Write-locality fix: the perm scatter footprint is 6.4 MB but round-2 traffic
// was E*66B = 106 MB because every XCD dirtied partial lines everywhere.
// Shard by dst range with shard = blockIdx & 7 (round-robin block->XCD), so
// each XCD's writes land in a private ~800 KB perm window + 50 KB cursor
// window that stay resident in its own L2 and write back once. Each shard
// re-scans the whole edge list (filter), but ei is L3-resident after the
// first pass, so the HBM read cost is paid once.
__global__ __launch_bounds__(256) void build_perm(const int* __restrict__ flags,
                                                  const int* __restrict__ ei,
                                                  int* __restrict__ cursor,
                                                  int* __restrict__ perm, int E) {
    const int shard = blockIdx.x & (NSHARD - 1);
    const int jb    = blockIdx.x >> 3;
    const int nb    = gridDim.x >> 3;
    const int lo = shard * SHARD_W;
    const int hi = lo + SHARD_W;                 // N divides evenly
    const int i64 = flags[1];
    for (long e = (long)jb * 256 + threadIdx.x; e < E; e += (long)nb * 256) {
        int d = i64 ? ei[2L * E + 2L * e] : ei[(long)E + e];
        if (d >= lo && d < hi) {
            int s = i64 ? ei[2L * e] : ei[e];
            int slot = atomicAdd(&cursor[d], 1);
            perm[slot] = s;
        }
    }
}

// ------------------------------------------------- h' = (x @ W) * dis -------
__global__ __launch_bounds__(256) void gemm_xw(const int* __restrict__ flags,
                                               const void* __restrict__ x_any,
                                               const ushort* __restrict__ W_raw,
                                               const ushort* __restrict__ wb,
                                               const float* __restrict__ dis,
                                               ushort* __restrict__ hout) {
    __shared__ __align__(16) ushort wt[128][128 + 8];   // 34816 B
    const int f32f = flags[0];
    const ushort* W = f32f ? wb : W_raw;

    const int tid  = threadIdx.x;
    const int lane = tid & 63;
    const int wave = tid >> 6;
    const int quad = lane >> 4;
    const int lm   = lane & 15;

    const int rbase = blockIdx.x * 64 + wave * 16;
    int arow = rbase + lm;
    if (arow >= N_NODES) arow = N_NODES - 1;      // clamp; store is guarded
    const float*  xrf = (const float*) x_any + (size_t)arow * F_IN;
    const ushort* xrb = (const ushort*)x_any + (size_t)arow * F_IN;

    float4v acc[8];
#pragma unroll
    for (int c = 0; c < 8; ++c) acc[c] = (float4v){0.f, 0.f, 0.f, 0.f};

    for (int hh = 0; hh < 2; ++hh) {
        if (hh) __syncthreads();
#pragma unroll
        for (int it = 0; it < 8; ++it) {
            int flat = (it * 256 + tid) * 8;       // 0..16384
            int kl = flat >> 7;
            int c0 = flat & 127;
            short8 v = *(const short8*)(W + hh * 16384 + flat);
#pragma unroll
            for (int j = 0; j < 8; ++j) wt[c0 + j][kl] = (ushort)v[j];
        }
        __syncthreads();
#pragma unroll
        for (int s = 0; s < 4; ++s) {
            int klocal = s * 32 + quad * 8;
            short8 afrag;
            if (f32f) {
                const float* p = xrf + hh * 128 + klocal;
                float4 u0 = *(const float4*)p;
                float4 u1 = *(const float4*)(p + 4);
                afrag[0] = (short)f2b(u0.x); afrag[1] = (short)f2b(u0.y);
                afrag[2] = (short)f2b(u0.z); afrag[3] = (short)f2b(u0.w);
                afrag[4] = (short)f2b(u1.x); afrag[5] = (short)f2b(u1.y);
                afrag[6] = (short)f2b(u1.z); afrag[7] = (short)f2b(u1.w);
            } else {
                afrag = *(const short8*)(xrb + hh * 128 + klocal);
            }
#pragma unroll
            for (int c = 0; c < 8; ++c) {
                short8 bfrag = *(const short8*)(&wt[c * 16 + lm][klocal]);
                acc[c] = __builtin_amdgcn_mfma_f32_16x16x32_bf16(afrag, bfrag, acc[c], 0, 0, 0);
            }
        }
    }
    // D[row=quad*4+r][col=lane&15]; scale rows by dis[node] before rounding
    float dv[4];
#pragma unroll
    for (int r = 0; r < 4; ++r) {
        int node = rbase + quad * 4 + r;
        dv[r] = (node < N_NODES) ? dis[node] : 0.f;
    }
#pragma unroll
    for (int c = 0; c < 8; ++c) {
        int col = c * 16 + lm;
#pragma unroll
        for (int r = 0; r < 4; ++r) {
            int node = rbase + quad * 4 + r;
            if (node < N_NODES) hout[(size_t)node * H_DIM + col] = f2b(acc[c][r] * dv[r]);
        }
    }
}

// --------------------- gather-reduce + bias + relu -> a (bf16) --------------
__global__ __launch_bounds__(256) void gather_relu(const int* __restrict__ offs,
                                                   const int* __restrict__ perm,
                                                   const float* __restrict__ dis,
                                                   const ushort* __restrict__ hb,
                                                   const float* __restrict__ gcnb_f,
                                                   ushort* __restrict__ aout) {
    const int lane = threadIdx.x & 63;
    const int node = blockIdx.x * 4 + (threadIdx.x >> 6);
    if (node >= N_NODES) return;

    const int off0 = __builtin_amdgcn_readfirstlane(offs[node]);
    const int deg  = __builtin_amdgcn_readfirstlane(offs[node + 1]) - off0;
    const int* pp = perm + off0;

    float ax = 0.f, ay = 0.f;
    const int full = deg & ~15;
    for (int base = 0; base < full; base += 16) {
#pragma unroll
        for (int k = 0; k < 16; ++k) {
            int sk = pp[base + k];                  // scalar 4B load (uniform)
            uint u = *((const uint*)(hb + (size_t)sk * H_DIM) + lane);
            ax += __uint_as_float(u << 16);
            ay += __uint_as_float(u & 0xFFFF0000u);
        }
    }
    {
        const int nb = deg - full;                  // 0..15, uniform
#pragma unroll
        for (int k = 0; k < 16; ++k) {
            int   sk = 0;
            float wk = 0.f;
            if (k < nb) { sk = pp[full + k]; wk = 1.f; }
            uint u = *((const uint*)(hb + (size_t)sk * H_DIM) + lane);
            ax = fmaf(wk, __uint_as_float(u << 16),         ax);
            ay = fmaf(wk, __uint_as_float(u & 0xFFFF0000u), ay);
        }
    }

    const float dd = dis[node];
    uint us = *((const uint*)(hb + (size_t)node * H_DIM) + lane);   // h'[node]
    float2 gb = *(const float2*)(gcnb_f + 2 * lane);
    ax = (ax + __uint_as_float(us << 16))         * dd + gb.x;
    ay = (ay + __uint_as_float(us & 0xFFFF0000u)) * dd + gb.y;
    ax = fmaxf(ax, 0.f);
    ay = fmaxf(ay, 0.f);
    uint pack = (uint)f2b(ax) | ((uint)f2b(ay) << 16);
    *((uint*)(aout + (size_t)node * H_DIM) + lane) = pack;
}

// -------------------- logits = a @ w^T + b, then log_softmax ----------------
__global__ __launch_bounds__(256) void final_linear(const int* __restrict__ flags,
                                                    const ushort* __restrict__ a,
                                                    const ushort* __restrict__ whi,
                                                    const ushort* __restrict__ wlo,
                                                    const float* __restrict__ bias16,
                                                    void* __restrict__ out) {
    const int f32f = flags[0];
    const int lane = threadIdx.x & 63;
    const int wave = threadIdx.x >> 6;
    const int n0 = (blockIdx.x * 4 + wave) * 16;
    if (n0 >= N_NODES) return;                 // 16 | N_NODES, no partial wave
    const int lm = lane & 15, quad = lane >> 4;

    const ushort* arow = a   + (size_t)(n0 + lm) * H_DIM + quad * 8;
    const ushort* bh   = whi + lm * H_DIM + quad * 8;
    const ushort* bl   = wlo + lm * H_DIM + quad * 8;

    float4v acc = (float4v){0.f, 0.f, 0.f, 0.f};
#pragma unroll
    for (int s = 0; s < 4; ++s) {
        short8 af = *(const short8*)(arow + s * 32);
        short8 b0 = *(const short8*)(bh   + s * 32);
        short8 b1 = *(const short8*)(bl   + s * 32);
        acc = __builtin_amdgcn_mfma_f32_16x16x32_bf16(af, b0, acc, 0, 0, 0);
        acc = __builtin_amdgcn_mfma_f32_16x16x32_bf16(af, b1, acc, 0, 0, 0);
    }

    const float bias = bias16[lm];
    float p[4], m[4], ss[4];
#pragma unroll
    for (int r = 0; r < 4; ++r) { p[r] = acc[r] + bias; m[r] = p[r]; }
#pragma unroll
    for (int off = 1; off < 16; off <<= 1)
#pragma unroll
        for (int r = 0; r < 4; ++r) m[r] = fmaxf(m[r], __shfl_xor(m[r], off, 64));
#pragma unroll
    for (int r = 0; r < 4; ++r) ss[r] = __expf(p[r] - m[r]);
#pragma unroll
    for (int off = 1; off < 16; off <<= 1)
#pragma unroll
        for (int r = 0; r < 4; ++r) ss[r] += __shfl_xor(ss[r], off, 64);

    if (f32f) {
        float* op = (float*)out;
#pragma unroll
        for (int r = 0; r < 4; ++r)
            op[(size_t)(n0 + quad * 4 + r) * C_CLS + lm] = p[r] - m[r] - __logf(ss[r]);
    } else {
        ushort* op = (ushort*)out;
#pragma unroll
        for (int r = 0; r < 4; ++r)
            op[(size_t)(n0 + quad * 4 + r) * C_CLS + lm] = f2b(p[r] - m[r] - __logf(ss[r]));
    }
}

// ---------------------------------------------------------------------------
extern "C" void kernel_launch(void* const* d_in, const int* in_sizes, int n_in,
                              void* d_out, int out_size, void* d_ws, size_t ws_size,
                              hipStream_t stream) {
    const int E = in_sizes[1] / 2;

    char* wp = (char*)d_ws;
    auto alloc = [&](size_t bytes) -> char* {
        char* p = wp; wp += (bytes + 511) & ~(size_t)511; return p;
    };
    int*    flags  = (int*)   alloc(64);
    ushort* hb     = (ushort*)alloc((size_t)N_NODES * H_DIM * 2);   // bf16 h*dis
    ushort* aout   = (ushort*)alloc((size_t)N_NODES * H_DIM * 2);   // bf16 relu(agg)
    int*    cnt    = (int*)   alloc((size_t)N_NODES * 4);
    int*    offs   = (int*)   alloc((size_t)(N_NODES + 1) * 4);
    int*    cursor = (int*)   alloc((size_t)N_NODES * 4);
    int*    bsum   = (int*)   alloc((size_t)NB_SCAN * 4);
    int*    boff   = (int*)   alloc((size_t)NB_SCAN * 4);
    float*  dis    = (float*) alloc((size_t)N_NODES * 4);
    int*    perm   = (int*)   alloc((size_t)E * 4);                 // src only
    ushort* wb     = (ushort*)alloc((size_t)F_IN * H_DIM * 2);
    ushort* whi    = (ushort*)alloc((size_t)C_CLS * H_DIM * 2);
    ushort* wlo    = (ushort*)alloc((size_t)C_CLS * H_DIM * 2);
    float*  bias16 = (float*) alloc((size_t)C_CLS * 4);
    float*  gcnb_f = (float*) alloc((size_t)H_DIM * 4);

    sniff<<<1, 64, 0, stream>>>((const ushort*)d_in[0], (const int*)d_in[1], flags);
    convert_w<<<(F_IN * H_DIM / 4 + 255) / 256, 256, 0, stream>>>(
        flags, (const float*)d_in[2], wb);
    make_w<<<1, 512, 0, stream>>>(flags, d_in[4], d_in[5], d_in[8],
                                  d_in[6], d_in[7], d_in[9], d_in[3],
                                  whi, wlo, bias16, gcnb_f);
    (void)hipMemsetAsync(cnt, 0, (size_t)N_NODES * 4, stream);
    prep<<<(E + 255) / 256, 256, 0, stream>>>(flags, (const int*)d_in[1], cnt, E);
    scan1<<<NB_SCAN, 256, 0, stream>>>(cnt, offs, bsum);
    scan2<<<1, 512, 0, stream>>>(bsum, boff);
    scan3<<<NB_SCAN, 256, 0, stream>>>(offs, boff, cnt, cursor, dis, E);
    build_perm<<<2048, 256, 0, stream>>>(flags, (const int*)d_in[1], cursor, perm, E);
    gemm_xw<<<(N_NODES + 63) / 64, 256, 0, stream>>>(flags, d_in[0],
                 (const ushort*)d_in[2], wb, dis, hb);
    gather_relu<<<(N_NODES + 3) / 4, 256, 0, stream>>>(offs, perm, dis, hb, gcnb_f, aout);
    final_linear<<<(N_NODES / C_CLS + 3) / 4, 256, 0, stream>>>(flags, aout, whi, wlo, bias16, (void*)d_out);
}

// Round 4
// 413.781 us; speedup vs baseline: 1.1577x; 1.0523x over previous
//
#include <hip/hip_runtime.h>
#include <hip/hip_bf16.h>

#define N_NODES 100000
#define F_IN    256
#define H_DIM   128
#define C_CLS   16
#define NB_SCAN ((N_NODES + 255) / 256)   // 391
#define NSHARD  8
#define SHARD_W ((N_NODES + NSHARD - 1) / NSHARD)   // 12500

typedef __attribute__((ext_vector_type(8))) short  short8;
typedef __attribute__((ext_vector_type(4))) float  float4v;
typedef __attribute__((ext_vector_type(4))) unsigned short ushort4v;

__device__ __forceinline__ float b2f(ushort u) {
    union { unsigned int i; float f; } v;
    v.i = ((unsigned int)u) << 16;
    return v.f;
}

__device__ __forceinline__ ushort f2b(float f) {
    unsigned int x = __float_as_uint(f);
    unsigned int r = (x + 0x7FFFu + ((x >> 16) & 1u)) >> 16;   // RNE
    return (ushort)r;
}

__device__ __forceinline__ float ldsel(const void* p, int i, int f32f) {
    return f32f ? ((const float*)p)[i] : b2f(((const ushort*)p)[i]);
}

// ------------------------------------------------------------------ sniff ---
__global__ __launch_bounds__(64) void sniff(const ushort* __restrict__ x,
                                            const int* __restrict__ ei,
                                            int* __restrict__ flags) {
    int lane = threadIdx.x;
    int cnt_bf = 0;
#pragma unroll
    for (int j = 0; j < 4; ++j) {
        ushort u = x[lane * 4 + j];
        int e = (u >> 7) & 0xFF;
        if ((e >= 100 && e <= 140) || (u & 0x7FFF) == 0) cnt_bf++;
    }
    int zodd = (ei[2 * lane + 1] == 0) ? 1 : 0;
#pragma unroll
    for (int off = 32; off >= 1; off >>= 1) {
        cnt_bf += __shfl_xor(cnt_bf, off, 64);
        zodd   += __shfl_xor(zodd,   off, 64);
    }
    if (lane == 0) {
        flags[0] = (cnt_bf < 230) ? 1 : 0;   // f32 inputs
        flags[1] = (zodd  >= 32) ? 1 : 0;    // int64 indices
    }
}

// ----------------------- wtg = W^T (bf16 [H][F_IN]), any input dtype --------
// Block n builds output row n (column n of W); thread t = k. Reads are
// column-strided (L2-absorbed, W is only 128 KB); writes coalesced 512B.
__global__ __launch_bounds__(256) void prep_w(const int* __restrict__ flags,
                                              const void* __restrict__ W_any,
                                              ushort* __restrict__ wtg) {
    const int f32f = flags[0];
    const int n = blockIdx.x;      // 0..127
    const int k = threadIdx.x;     // 0..255
    float v = f32f ? ((const float*)W_any)[k * H_DIM + n]
                   : b2f(((const ushort*)W_any)[k * H_DIM + n]);
    wtg[n * F_IN + k] = f2b(v);
}

// ------------- precompute bayes weights (bf16 hi+lo), bias, gcn bias --------
__global__ __launch_bounds__(512) void make_w(const int* __restrict__ flags,
                                              const void* __restrict__ w_mu,
                                              const void* __restrict__ w_ls,
                                              const void* __restrict__ eps_w,
                                              const void* __restrict__ b_mu,
                                              const void* __restrict__ b_ls,
                                              const void* __restrict__ eps_b,
                                              const void* __restrict__ gcn_b,
                                              ushort* __restrict__ whi,
                                              ushort* __restrict__ wlo,
                                              float* __restrict__ bias16,
                                              float* __restrict__ gcnb_f) {
    const int f32f = flags[0];
    const int t = threadIdx.x;
#pragma unroll
    for (int i = t; i < C_CLS * H_DIM; i += 512) {
        float v = ldsel(w_mu, i, f32f) + __expf(ldsel(w_ls, i, f32f)) * ldsel(eps_w, i, f32f);
        ushort h = f2b(v);
        whi[i] = h;
        wlo[i] = f2b(v - b2f(h));     // residual: recovers ~16-bit mantissa
    }
    if (t < C_CLS)
        bias16[t] = ldsel(b_mu, t, f32f) + __expf(ldsel(b_ls, t, f32f)) * ldsel(eps_b, t, f32f);
    if (t < H_DIM)
        gcnb_f[t] = ldsel(gcn_b, t, f32f);
}

// ---------------------- prep: degree count only (reads dst half of ei) ------
__global__ __launch_bounds__(256) void prep(const int* __restrict__ flags,
                                            const int* __restrict__ ei,
                                            int* __restrict__ cnt, int E) {
    int e = blockIdx.x * 256 + threadIdx.x;
    if (e >= E) return;
    int d = flags[1] ? ei[2L * E + 2L * e] : ei[(long)E + e];
    atomicAdd(&cnt[d], 1);
}

// ------------------------------------------------------------ 3-step scan ---
__global__ __launch_bounds__(256) void scan1(const int* __restrict__ cnt,
                                             int* __restrict__ offs,
                                             int* __restrict__ bsum) {
    __shared__ int sd[256];
    int t = threadIdx.x;
    int i = blockIdx.x * 256 + t;
    int v = (i < N_NODES) ? cnt[i] : 0;
    sd[t] = v;
    __syncthreads();
#pragma unroll
    for (int d = 1; d < 256; d <<= 1) {
        int add = (t >= d) ? sd[t - d] : 0;
        __syncthreads();
        sd[t] += add;
        __syncthreads();
    }
    if (i < N_NODES) offs[i] = sd[t] - v;          // exclusive within block
    if (t == 255) bsum[blockIdx.x] = sd[255];
}

__global__ __launch_bounds__(512) void scan2(const int* __restrict__ bsum,
                                             int* __restrict__ boff) {
    __shared__ int sd[512];
    int t = threadIdx.x;
    int v = (t < NB_SCAN) ? bsum[t] : 0;
    sd[t] = v;
    __syncthreads();
#pragma unroll
    for (int d = 1; d < 512; d <<= 1) {
        int add = (t >= d) ? sd[t - d] : 0;
        __syncthreads();
        sd[t] += add;
        __syncthreads();
    }
    if (t < NB_SCAN) boff[t] = sd[t] - v;          // exclusive
}

// offs -> global offsets; also cursor copy and dis = rsqrt(deg) fused
__global__ __launch_bounds__(256) void scan3(int* __restrict__ offs,
                                             const int* __restrict__ boff,
                                             const int* __restrict__ cnt,
                                             int* __restrict__ cursor,
                                             float* __restrict__ dis, int E) {
    int i = blockIdx.x * 256 + threadIdx.x;
    if (i == 0) offs[N_NODES] = E;
    if (i >= N_NODES) return;
    int off = offs[i] + boff[i >> 8];
    offs[i] = off;
    cursor[i] = off;
    dis[i] = rsqrtf((float)(cnt[i] + 1));          // +1 self-loop
}

// ---------------------------------- XCD-sharded permutation build -----------
// shard = blockIdx & 7 (round-robin block->XCD): each XCD's scatter writes
// land in a private ~800 KB perm window + 50 KB cursor window, L2-resident.
// Each shard rescans ei (L3-resident after first pass).
__global__ __launch_bounds__(256) void build_perm(const int* __restrict__ flags,
                                                  const int* __restrict__ ei,
                                                  int* __restrict__ cursor,
                                                  int* __restrict__ perm, int E) {
    const int shard = blockIdx.x & (NSHARD - 1);
    const int jb    = blockIdx.x >> 3;
    const int nb    = gridDim.x >> 3;
    const int lo = shard * SHARD_W;
    const int hi = lo + SHARD_W;                 // N divides evenly
    const int i64 = flags[1];
    for (long e = (long)jb * 256 + threadIdx.x; e < E; e += (long)nb * 256) {
        int d = i64 ? ei[2L * E + 2L * e] : ei[(long)E + e];
        if (d >= lo && d < hi) {
            int s = i64 ? ei[2L * e] : ei[e];
            int slot = atomicAdd(&cursor[d], 1);
            perm[slot] = s;
        }
    }
}

// ------------------------------------------------- h' = (x @ W) * dis -------
// W comes pre-transposed (wtg); LDS staging is a pure short8 copy into an
// XOR-swizzled flat layout: idx = ((col<<7)|k) ^ ((col&7)<<3). Both write and
// read sides use the same swizzle -> aligned b128 ops at the minimum
// 8 dword-accesses/bank (was: 128 scalar ds_write_b16/thread at 16-way).
__global__ __launch_bounds__(256) void gemm_xw(const int* __restrict__ flags,
                                               const void* __restrict__ x_any,
                                               const ushort* __restrict__ wtg,
                                               const float* __restrict__ dis,
                                               ushort* __restrict__ hout) {
    __shared__ __align__(16) ushort wt[128 * 128];      // 32768 B
    const int f32f = flags[0];

    const int tid  = threadIdx.x;
    const int lane = tid & 63;
    const int quad = lane >> 4;
    const int lm   = lane & 15;
    const int wave = tid >> 6;

    const int rbase = blockIdx.x * 64 + wave * 16;
    int arow = rbase + lm;
    if (arow >= N_NODES) arow = N_NODES - 1;      // clamp; store is guarded
    const float*  xrf = (const float*) x_any + (size_t)arow * F_IN;
    const ushort* xrb = (const ushort*)x_any + (size_t)arow * F_IN;

    float4v acc[8];
#pragma unroll
    for (int c = 0; c < 8; ++c) acc[c] = (float4v){0.f, 0.f, 0.f, 0.f};

    for (int hh = 0; hh < 2; ++hh) {
        if (hh) __syncthreads();
#pragma unroll
        for (int it = 0; it < 8; ++it) {
            int flat = (it * 256 + tid) * 8;       // ushort idx, 0..16376
            int col  = flat >> 7;
            int kloc = flat & 127;
            short8 v = *(const short8*)(wtg + col * F_IN + hh * 128 + kloc);
            int dst = ((col << 7) | kloc) ^ ((col & 7) << 3);
            *(short8*)(wt + dst) = v;
        }
        __syncthreads();
#pragma unroll
        for (int s = 0; s < 4; ++s) {
            int klocal = s * 32 + quad * 8;
            short8 afrag;
            if (f32f) {
                const float* p = xrf + hh * 128 + klocal;
                float4 u0 = *(const float4*)p;
                float4 u1 = *(const float4*)(p + 4);
                afrag[0] = (short)f2b(u0.x); afrag[1] = (short)f2b(u0.y);
                afrag[2] = (short)f2b(u0.z); afrag[3] = (short)f2b(u0.w);
                afrag[4] = (short)f2b(u1.x); afrag[5] = (short)f2b(u1.y);
                afrag[6] = (short)f2b(u1.z); afrag[7] = (short)f2b(u1.w);
            } else {
                afrag = *(const short8*)(xrb + hh * 128 + klocal);
            }
#pragma unroll
            for (int c = 0; c < 8; ++c) {
                int colr = c * 16 + lm;
                int src = ((colr << 7) | klocal) ^ ((lm & 7) << 3);
                short8 bfrag = *(const short8*)(wt + src);
                acc[c] = __builtin_amdgcn_mfma_f32_16x16x32_bf16(afrag, bfrag, acc[c], 0, 0, 0);
            }
        }
    }
    // D[row=quad*4+r][col=lane&15]; scale rows by dis[node] before rounding
    float dv[4];
#pragma unroll
    for (int r = 0; r < 4; ++r) {
        int node = rbase + quad * 4 + r;
        dv[r] = (node < N_NODES) ? dis[node] : 0.f;
    }
#pragma unroll
    for (int c = 0; c < 8; ++c) {
        int col = c * 16 + lm;
#pragma unroll
        for (int r = 0; r < 4; ++r) {
            int node = rbase + quad * 4 + r;
            if (node < N_NODES) hout[(size_t)node * H_DIM + col] = f2b(acc[c][r] * dv[r]);
        }
    }
}

// --------------------- gather-reduce + bias + relu -> a (bf16) --------------
__global__ __launch_bounds__(256) void gather_relu(const int* __restrict__ offs,
                                                   const int* __restrict__ perm,
                                                   const float* __restrict__ dis,
                                                   const ushort* __restrict__ hb,
                                                   const float* __restrict__ gcnb_f,
                                                   ushort* __restrict__ aout) {
    const int lane = threadIdx.x & 63;
    const int node = blockIdx.x * 4 + (threadIdx.x >> 6);
    if (node >= N_NODES) return;

    const int off0 = __builtin_amdgcn_readfirstlane(offs[node]);
    const int deg  = __builtin_amdgcn_readfirstlane(offs[node + 1]) - off0;
    const int* pp = perm + off0;

    float ax = 0.f, ay = 0.f;
    const int full = deg & ~15;
    for (int base = 0; base < full; base += 16) {
#pragma unroll
        for (int k = 0; k < 16; ++k) {
            int sk = pp[base + k];                  // scalar 4B load (uniform)
            uint u = *((const uint*)(hb + (size_t)sk * H_DIM) + lane);
            ax += __uint_as_float(u << 16);
            ay += __uint_as_float(u & 0xFFFF0000u);
        }
    }
    {
        const int nb = deg - full;                  // 0..15, uniform
#pragma unroll
        for (int k = 0; k < 16; ++k) {
            int   sk = 0;
            float wk = 0.f;
            if (k < nb) { sk = pp[full + k]; wk = 1.f; }
            uint u = *((const uint*)(hb + (size_t)sk * H_DIM) + lane);
            ax = fmaf(wk, __uint_as_float(u << 16),         ax);
            ay = fmaf(wk, __uint_as_float(u & 0xFFFF0000u), ay);
        }
    }

    const float dd = dis[node];
    uint us = *((const uint*)(hb + (size_t)node * H_DIM) + lane);   // h'[node]
    float2 gb = *(const float2*)(gcnb_f + 2 * lane);
    ax = (ax + __uint_as_float(us << 16))         * dd + gb.x;
    ay = (ay + __uint_as_float(us & 0xFFFF0000u)) * dd + gb.y;
    ax = fmaxf(ax, 0.f);
    ay = fmaxf(ay, 0.f);
    uint pack = (uint)f2b(ax) | ((uint)f2b(ay) << 16);
    *((uint*)(aout + (size_t)node * H_DIM) + lane) = pack;
}

// -------------------- logits = a @ w^T + b, then log_softmax ----------------
__global__ __launch_bounds__(256) void final_linear(const int* __restrict__ flags,
                                                    const ushort* __restrict__ a,
                                                    const ushort* __restrict__ whi,
                                                    const ushort* __restrict__ wlo,
                                                    const float* __restrict__ bias16,
                                                    void* __restrict__ out) {
    const int f32f = flags[0];
    const int lane = threadIdx.x & 63;
    const int wave = threadIdx.x >> 6;
    const int n0 = (blockIdx.x * 4 + wave) * 16;
    if (n0 >= N_NODES) return;                 // 16 | N_NODES, no partial wave
    const int lm = lane & 15, quad = lane >> 4;

    const ushort* arow = a   + (size_t)(n0 + lm) * H_DIM + quad * 8;
    const ushort* bh   = whi + lm * H_DIM + quad * 8;
    const ushort* bl   = wlo + lm * H_DIM + quad * 8;

    float4v acc = (float4v){0.f, 0.f, 0.f, 0.f};
#pragma unroll
    for (int s = 0; s < 4; ++s) {
        short8 af = *(const short8*)(arow + s * 32);
        short8 b0 = *(const short8*)(bh   + s * 32);
        short8 b1 = *(const short8*)(bl   + s * 32);
        acc = __builtin_amdgcn_mfma_f32_16x16x32_bf16(af, b0, acc, 0, 0, 0);
        acc = __builtin_amdgcn_mfma_f32_16x16x32_bf16(af, b1, acc, 0, 0, 0);
    }

    const float bias = bias16[lm];
    float p[4], m[4], ss[4];
#pragma unroll
    for (int r = 0; r < 4; ++r) { p[r] = acc[r] + bias; m[r] = p[r]; }
#pragma unroll
    for (int off = 1; off < 16; off <<= 1)
#pragma unroll
        for (int r = 0; r < 4; ++r) m[r] = fmaxf(m[r], __shfl_xor(m[r], off, 64));
#pragma unroll
    for (int r = 0; r < 4; ++r) ss[r] = __expf(p[r] - m[r]);
#pragma unroll
    for (int off = 1; off < 16; off <<= 1)
#pragma unroll
        for (int r = 0; r < 4; ++r) ss[r] += __shfl_xor(ss[r], off, 64);

    if (f32f) {
        float* op = (float*)out;
#pragma unroll
        for (int r = 0; r < 4; ++r)
            op[(size_t)(n0 + quad * 4 + r) * C_CLS + lm] = p[r] - m[r] - __logf(ss[r]);
    } else {
        ushort* op = (ushort*)out;
#pragma unroll
        for (int r = 0; r < 4; ++r)
            op[(size_t)(n0 + quad * 4 + r) * C_CLS + lm] = f2b(p[r] - m[r] - __logf(ss[r]));
    }
}

// ---------------------------------------------------------------------------
extern "C" void kernel_launch(void* const* d_in, const int* in_sizes, int n_in,
                              void* d_out, int out_size, void* d_ws, size_t ws_size,
                              hipStream_t stream) {
    const int E = in_sizes[1] / 2;

    char* wp = (char*)d_ws;
    auto alloc = [&](size_t bytes) -> char* {
        char* p = wp; wp += (bytes + 511) & ~(size_t)511; return p;
    };
    int*    flags  = (int*)   alloc(64);
    ushort* hb     = (ushort*)alloc((size_t)N_NODES * H_DIM * 2);   // bf16 h*dis
    ushort* aout   = (ushort*)alloc((size_t)N_NODES * H_DIM * 2);   // bf16 relu(agg)
    int*    cnt    = (int*)   alloc((size_t)N_NODES * 4);
    int*    offs   = (int*)   alloc((size_t)(N_NODES + 1) * 4);
    int*    cursor = (int*)   alloc((size_t)N_NODES * 4);
    int*    bsum   = (int*)   alloc((size_t)NB_SCAN * 4);
    int*    boff   = (int*)   alloc((size_t)NB_SCAN * 4);
    float*  dis    = (float*) alloc((size_t)N_NODES * 4);
    int*    perm   = (int*)   alloc((size_t)E * 4);                 // src only
    ushort* wtg    = (ushort*)alloc((size_t)H_DIM * F_IN * 2);      // W^T bf16
    ushort* whi    = (ushort*)alloc((size_t)C_CLS * H_DIM * 2);
    ushort* wlo    = (ushort*)alloc((size_t)C_CLS * H_DIM * 2);
    float*  bias16 = (float*) alloc((size_t)C_CLS * 4);
    float*  gcnb_f = (float*) alloc((size_t)H_DIM * 4);

    sniff<<<1, 64, 0, stream>>>((const ushort*)d_in[0], (const int*)d_in[1], flags);
    prep_w<<<H_DIM, 256, 0, stream>>>(flags, d_in[2], wtg);
    make_w<<<1, 512, 0, stream>>>(flags, d_in[4], d_in[5], d_in[8],
                                  d_in[6], d_in[7], d_in[9], d_in[3],
                                  whi, wlo, bias16, gcnb_f);
    (void)hipMemsetAsync(cnt, 0, (size_t)N_NODES * 4, stream);
    prep<<<(E + 255) / 256, 256, 0, stream>>>(flags, (const int*)d_in[1], cnt, E);
    scan1<<<NB_SCAN, 256, 0, stream>>>(cnt, offs, bsum);
    scan2<<<1, 512, 0, stream>>>(bsum, boff);
    scan3<<<NB_SCAN, 256, 0, stream>>>(offs, boff, cnt, cursor, dis, E);
    build_perm<<<2048, 256, 0, stream>>>(flags, (const int*)d_in[1], cursor, perm, E);
    gemm_xw<<<(N_NODES + 63) / 64, 256, 0, stream>>>(flags, d_in[0], wtg, dis, hb);
    gather_relu<<<(N_NODES + 3) / 4, 256, 0, stream>>>(offs, perm, dis, hb, gcnb_f, aout);
    final_linear<<<(N_NODES / C_CLS + 3) / 4, 256, 0, stream>>>(flags, aout, whi, wlo, bias16, (void*)d_out);
}